// Round 8
// baseline (369.085 us; speedup 1.0000x reference)
//
#include <hip/hip_runtime.h>
#include <hip/hip_bf16.h>

#define LN2F 0.69314718055994530942f

typedef short bf16x8 __attribute__((ext_vector_type(8)));
typedef float f32x4  __attribute__((ext_vector_type(4)));

__device__ __forceinline__ float ssp_f(float t){
  // softplus(t) - ln2, numerically stable
  return fmaxf(t, 0.0f) + __logf(1.0f + __expf(-fabsf(t))) - LN2F;
}
__device__ __forceinline__ unsigned short f2bf_u(float f){
  __hip_bfloat16 b = __float2bfloat16(f);
  return *reinterpret_cast<unsigned short*>(&b);
}
__device__ __forceinline__ float bf2f(unsigned short u){
  __hip_bfloat16 b = *reinterpret_cast<__hip_bfloat16*>(&u);
  return __bfloat162float(b);
}

__device__ __forceinline__ int load_idx(const void* ei, int is32, size_t pos){
  return is32 ? ((const int*)ei)[pos] : (int)(((const long long*)ei)[pos]);
}

// ---------------- setup: zero count + (block 0) index width detection ------
__global__ __launch_bounds__(256) void setup_kernel(const unsigned* __restrict__ ei,
                                                    int* __restrict__ flag,
                                                    int* __restrict__ count, int N){
  int i = blockIdx.x * 256 + threadIdx.x;
  if (i < N) count[i] = 0;
  if (blockIdx.x == 0){
    __shared__ int cnt;
    if (threadIdx.x == 0) cnt = 0;
    __syncthreads();
    int nz = 0;
    for (int k = threadIdx.x; k < 1024; k += 256)
      nz += (ei[2*k + 1] != 0u) ? 1 : 0;
    atomicAdd(&cnt, nz);
    __syncthreads();
    // int32 data: odd words are real indices (~all nonzero). int64: high words 0.
    if (threadIdx.x == 0) *flag = (cnt > 64) ? 1 : 0;
  }
}

// ---------------- CSR build ------------------------------------------------
__global__ void hist_kernel(const void* __restrict__ ei, const int* __restrict__ flag,
                            int* __restrict__ count, int E){
  const int is32 = *flag;
  for (long long e = (long long)blockIdx.x * 256 + threadIdx.x; e < E;
       e += (long long)gridDim.x * 256){
    int d = load_idx(ei, is32, (size_t)((long long)E + e));
    atomicAdd(&count[d], 1);
  }
}

// three-pass scan: block sums -> serial scan of block sums -> local scan
__global__ __launch_bounds__(256) void scan1_kernel(const int* __restrict__ count,
                                                    int* __restrict__ bsum, int N){
  __shared__ int red[256];
  const int t = threadIdx.x;
  int i0 = blockIdx.x * 2048 + t * 8;
  int s = 0;
  #pragma unroll
  for (int r = 0; r < 8; ++r){ int i = i0 + r; s += (i < N) ? count[i] : 0; }
  red[t] = s;
  __syncthreads();
  for (int off = 128; off > 0; off >>= 1){
    if (t < off) red[t] += red[t + off];
    __syncthreads();
  }
  if (t == 0) bsum[blockIdx.x] = red[0];
}

__global__ void scan2_kernel(int* __restrict__ bsum, int* __restrict__ offs, int nb, int N){
  if (threadIdx.x == 0 && blockIdx.x == 0){
    int run = 0;
    for (int b = 0; b < nb; ++b){ int v = bsum[b]; bsum[b] = run; run += v; }
    offs[N] = run;
  }
}

__global__ __launch_bounds__(256) void scan3_kernel(const int* __restrict__ count,
                                                    const int* __restrict__ bsum,
                                                    int* __restrict__ offs,
                                                    int* __restrict__ cur, int N){
  __shared__ int red[256];
  const int t = threadIdx.x;
  int i0 = blockIdx.x * 2048 + t * 8;
  int v[8];
  int s = 0;
  #pragma unroll
  for (int r = 0; r < 8; ++r){ int i = i0 + r; v[r] = (i < N) ? count[i] : 0; s += v[r]; }
  red[t] = s;
  __syncthreads();
  #pragma unroll
  for (int off = 1; off < 256; off <<= 1){
    int tv = (t >= off) ? red[t - off] : 0;
    __syncthreads();
    red[t] += tv;
    __syncthreads();
  }
  int run = red[t] - s + bsum[blockIdx.x];
  #pragma unroll
  for (int r = 0; r < 8; ++r){
    int i = i0 + r;
    if (i < N){ offs[i] = run; cur[i] = run; }
    run += v[r];
  }
}

// se[slot] = (e, src), slots sorted by dst (CSR order)
__global__ void fill_kernel(const void* __restrict__ ei, const int* __restrict__ flag,
                            int* __restrict__ cur, int2* __restrict__ se, int E){
  const int is32 = *flag;
  for (long long e = (long long)blockIdx.x * 256 + threadIdx.x; e < E;
       e += (long long)gridDim.x * 256){
    int s = load_idx(ei, is32, (size_t)e);
    int d = load_idx(ei, is32, (size_t)((long long)E + e));
    int slot = atomicAdd(&cur[d], 1);
    se[slot] = make_int2((int)e, s);
  }
}

// ---------------- weight prep: fp32 row-major -> bf16 MFMA-fragment-linear --
// wfrag: q = ((ct*4+kt)*64 + lane)*8 + i <-> W[ct*16+(lane&15)][kt*32+(lane>>4)*8+i]
// wgfrag: q = ((((half*4+nt)*2+kt)*64)+lane)*8+i <-> WG[half*64+nt*16+(lane&15)][kt*32+(lane>>4)*8+i]
struct WPtrs { const float* w[16]; };

__global__ __launch_bounds__(256) void prep_kernel(WPtrs p, int nw,
    unsigned short* __restrict__ wfrag, const float* __restrict__ WG,
    unsigned short* __restrict__ wgfrag){
  const int m = blockIdx.x;
  if (m < nw){
    const float* __restrict__ W = p.w[m];
    unsigned short* __restrict__ out = wfrag + (size_t)m * 16384;
    for (int q = threadIdx.x; q < 16384; q += 256){
      int i = q & 7, lane = (q >> 3) & 63, kt = (q >> 9) & 3, ct = q >> 11;
      int row = ct*16 + (lane & 15);
      int k   = kt*32 + (lane >> 4)*8 + i;
      out[q] = f2bf_u(W[row*128 + k]);
    }
  } else {
    const int b = m - nw;                 // 0..3, each covers 2048 of 8192
    for (int qq = threadIdx.x; qq < 2048; qq += 256){
      int q = b*2048 + qq;
      int i = q & 7, lane = (q >> 3) & 63, kt = (q >> 9) & 1, nt = (q >> 10) & 3, half = q >> 12;
      int f = half*64 + nt*16 + (lane & 15);
      int k = kt*32 + (lane >> 4)*8 + i;
      wgfrag[q] = f2bf_u(WG[(size_t)f*64 + k]);
    }
  }
}

// ---------------- MFMA GEMM core: 128-row A tile (swizzled), K=128 --------
// A_s: bf16 [128][128], element (row,col) at row*128 + (col ^ ((row&7)<<3)).
// Bf: 16384 bf16 fragment-linear. acc[ct][q] = C[rbase+(lane>>4)*4+q][ct*16+(lane&15)]
__device__ __forceinline__ void mfma_gemm128s(const unsigned short* __restrict__ A_s,
                                              const unsigned short* __restrict__ Bf,
                                              int rbase, int lane, f32x4 acc[8]){
  #pragma unroll
  for (int ct = 0; ct < 8; ++ct) acc[ct] = (f32x4){0.f, 0.f, 0.f, 0.f};
  const int r  = rbase + (lane & 15);
  const int kg = lane >> 4;
  const int sw = (r & 7) << 3;
  #pragma unroll
  for (int kt = 0; kt < 4; ++kt){
    bf16x8 a = *(const bf16x8*)&A_s[r*128 + ((kt*32 + kg*8) ^ sw)];
    #pragma unroll
    for (int ct = 0; ct < 8; ++ct){
      bf16x8 b = *(const bf16x8*)&Bf[(size_t)((ct*4 + kt)*64 + lane)*8];
      acc[ct] = __builtin_amdgcn_mfma_f32_16x16x32_bf16(a, b, acc[ct], 0, 0, 0);
    }
  }
}

__device__ __forceinline__ void stage_bf512(unsigned short* __restrict__ Bf,
                                            const unsigned short* __restrict__ src, int t){
  #pragma unroll
  for (int it = 0; it < 4; ++it){
    int off = (it*512 + t) * 8;
    *(uint4*)&Bf[off] = *(const uint4*)&src[off];
  }
}

// ---------------- kernel 1: h = bf16(ssp(xa W_diff^T+b)), msged = ssp(xa W_same^T+b)
__global__ __launch_bounds__(512) void node_dual_kernel(
    const float* __restrict__ x, const unsigned short* __restrict__ wfrag,
    const float* __restrict__ bsame, const float* __restrict__ bdiff,
    unsigned short* __restrict__ hbf, float* __restrict__ msged, int N){
  __shared__ __align__(16) unsigned short A_s[128*128];
  __shared__ __align__(16) unsigned short Bf[16384];
  const int t = threadIdx.x, wv = t >> 6, lane = t & 63;
  const int kg = lane >> 4, c = lane & 15;
  const int row0 = blockIdx.x * 128;
  for (int q = t; q < 2048; q += 512){
    int row = q >> 4, c0 = (q & 15) * 8;
    float4 va = make_float4(0.f,0.f,0.f,0.f), vb = va;
    if (row0 + row < N){
      va = *(const float4*)&x[(size_t)(row0 + row)*128 + c0];
      vb = *(const float4*)&x[(size_t)(row0 + row)*128 + c0 + 4];
    }
    uint4 w;
    w.x = f2bf_u(ssp_f(va.x)) | ((unsigned)f2bf_u(ssp_f(va.y)) << 16);
    w.y = f2bf_u(ssp_f(va.z)) | ((unsigned)f2bf_u(ssp_f(va.w)) << 16);
    w.z = f2bf_u(ssp_f(vb.x)) | ((unsigned)f2bf_u(ssp_f(vb.y)) << 16);
    w.w = f2bf_u(ssp_f(vb.z)) | ((unsigned)f2bf_u(ssp_f(vb.w)) << 16);
    *(uint4*)&A_s[row*128 + (c0 ^ ((row & 7) << 3))] = w;
  }
  stage_bf512(Bf, wfrag, t);            // W_same
  __syncthreads();
  f32x4 acc[8];
  mfma_gemm128s(A_s, Bf, wv*16, lane, acc);
  #pragma unroll
  for (int ct = 0; ct < 8; ++ct){
    int col = ct*16 + c;
    float bv = bsame[col];
    #pragma unroll
    for (int q = 0; q < 4; ++q){
      int gr = row0 + wv*16 + kg*4 + q;
      if (gr < N) msged[(size_t)gr*128 + col] = ssp_f(acc[ct][q] + bv);
    }
  }
  __syncthreads();
  stage_bf512(Bf, wfrag + 16384, t);    // W_diff
  __syncthreads();
  mfma_gemm128s(A_s, Bf, wv*16, lane, acc);
  #pragma unroll
  for (int ct = 0; ct < 8; ++ct){
    int col = ct*16 + c;
    float bv = bdiff[col];
    #pragma unroll
    for (int q = 0; q < 4; ++q){
      int gr = row0 + wv*16 + kg*4 + q;
      if (gr < N) hbf[(size_t)gr*128 + col] = f2bf_u(ssp_f(acc[ct][q] + bv));
    }
  }
}

// ---------------- edge phase: swapped-operand MFMA gate + segmented reduce -
// acc = WG(A) x ea(B): lane holds (slot = lane&15, f = nt*16+kg*4+q) -> h is
// lane-local (own se), loaded as 4x ushort4; no shfls; se prefetched.
__global__ __launch_bounds__(256) void edge_mfma_kernel(
    const float* __restrict__ ea, const unsigned short* __restrict__ wgfrag,
    const unsigned short* __restrict__ h, const int2* __restrict__ se,
    const int* __restrict__ offs, float* __restrict__ msged, int N, int E, int KW){
  __shared__ float P_s[4][16][67];
  const int t = threadIdx.x, wv = t >> 6, lane = t & 63;
  const int kg = lane >> 4, c = lane & 15;
  const int gw = blockIdx.x * 4 + wv;
  const int half = gw & 1;
  const int widx = gw >> 1;
  if (widx >= KW) return;
  long long tt0 = (long long)widx * E / KW;
  long long tt1 = (long long)(widx + 1) * E / KW;
  int lo = 0, hi = N;
  while (lo < hi){ int mid = (lo + hi) >> 1; if ((long long)offs[mid] < tt0) lo = mid + 1; else hi = mid; }
  const int d_lo = lo;
  hi = N;
  while (lo < hi){ int mid = (lo + hi) >> 1; if ((long long)offs[mid] < tt1) lo = mid + 1; else hi = mid; }
  const int d_hi = lo;
  if (d_lo >= d_hi) return;
  const int s_beg = offs[d_lo], s_end = offs[d_hi];
  if (s_beg >= s_end) return;

  // preload this half's WG fragments (A operand; reused for all batches)
  bf16x8 aw[4][2];
  #pragma unroll
  for (int nt = 0; nt < 4; ++nt)
    #pragma unroll
    for (int kt = 0; kt < 2; ++kt)
      aw[nt][kt] = *(const bf16x8*)&wgfrag[(size_t)((((half*4+nt)*2+kt)*64)+lane)*8];

  // boundary tracking with prefetched next-next offset
  int d_cur = d_lo;
  int no0 = offs[d_cur + 1];
  while (no0 == s_beg && d_cur + 1 < d_hi){ ++d_cur; no0 = offs[d_cur + 1]; }
  int no1 = (d_cur + 2 <= d_hi) ? offs[d_cur + 2] : 0x7FFFFFFF;

  float sum_v = 0.f;
  int p = s_beg;
  int nb = min(16, s_end - p);
  int2 s2 = se[p + min(c, nb - 1)];
  while (p < s_end){
    const int pn = p + 16;
    int2 s2n = s2;
    if (pn < s_end){
      int nbn = min(16, s_end - pn);
      s2n = se[pn + min(c, nbn - 1)];
    }
    // B fragments: this lane's slot-c ea row, k slice kg*8..kg*8+7 (+kt*32)
    const float* __restrict__ ra = &ea[(size_t)s2.x * 64 + kg*8];
    float4 e00 = *(const float4*)&ra[0];
    float4 e01 = *(const float4*)&ra[4];
    float4 e10 = *(const float4*)&ra[32];
    float4 e11 = *(const float4*)&ra[36];
    // h: lane-local src row, f = nt*16 + kg*4 + (0..3)
    const unsigned short* __restrict__ hr = &h[(size_t)s2.y*128 + half*64 + kg*4];
    ushort4 hu0 = *(const ushort4*)&hr[0];
    ushort4 hu1 = *(const ushort4*)&hr[16];
    ushort4 hu2 = *(const ushort4*)&hr[32];
    ushort4 hu3 = *(const ushort4*)&hr[48];

    bf16x8 be0, be1;
    unsigned short* b0p = (unsigned short*)&be0;
    unsigned short* b1p = (unsigned short*)&be1;
    b0p[0]=f2bf_u(e00.x); b0p[1]=f2bf_u(e00.y); b0p[2]=f2bf_u(e00.z); b0p[3]=f2bf_u(e00.w);
    b0p[4]=f2bf_u(e01.x); b0p[5]=f2bf_u(e01.y); b0p[6]=f2bf_u(e01.z); b0p[7]=f2bf_u(e01.w);
    b1p[0]=f2bf_u(e10.x); b1p[1]=f2bf_u(e10.y); b1p[2]=f2bf_u(e10.z); b1p[3]=f2bf_u(e10.w);
    b1p[4]=f2bf_u(e11.x); b1p[5]=f2bf_u(e11.y); b1p[6]=f2bf_u(e11.z); b1p[7]=f2bf_u(e11.w);

    f32x4 acc[4];
    #pragma unroll
    for (int nt = 0; nt < 4; ++nt){
      acc[nt] = (f32x4){0.f,0.f,0.f,0.f};
      acc[nt] = __builtin_amdgcn_mfma_f32_16x16x32_bf16(aw[nt][0], be0, acc[nt], 0, 0, 0);
      acc[nt] = __builtin_amdgcn_mfma_f32_16x16x32_bf16(aw[nt][1], be1, acc[nt], 0, 0, 0);
    }

    float hvv[4][4];
    hvv[0][0]=bf2f(hu0.x); hvv[0][1]=bf2f(hu0.y); hvv[0][2]=bf2f(hu0.z); hvv[0][3]=bf2f(hu0.w);
    hvv[1][0]=bf2f(hu1.x); hvv[1][1]=bf2f(hu1.y); hvv[1][2]=bf2f(hu1.z); hvv[1][3]=bf2f(hu1.w);
    hvv[2][0]=bf2f(hu2.x); hvv[2][1]=bf2f(hu2.y); hvv[2][2]=bf2f(hu2.z); hvv[2][3]=bf2f(hu2.w);
    hvv[3][0]=bf2f(hu3.x); hvv[3][1]=bf2f(hu3.y); hvv[3][2]=bf2f(hu3.z); hvv[3][3]=bf2f(hu3.w);

    // P[slot=c][f'] = gate * h   (2-way bank pattern on [16][67], free)
    #pragma unroll
    for (int nt = 0; nt < 4; ++nt)
      #pragma unroll
      for (int q = 0; q < 4; ++q)
        P_s[wv][c][nt*16 + kg*4 + q] = acc[nt][q] * hvv[nt][q];

    asm volatile("s_waitcnt lgkmcnt(0)" ::: "memory");  // P_s visible; vmcnt prefetch survives

    const int nbc = min(16, s_end - p);
    for (int i = 0; i < nbc; ++i){
      sum_v += P_s[wv][i][lane];
      if (p + i + 1 == no0){
        msged[(size_t)d_cur*128 + half*64 + lane] += sum_v;   // owner-exclusive
        sum_v = 0.f;
        do {
          ++d_cur;
          no0 = no1;
          no1 = (d_cur + 2 <= d_hi) ? offs[d_cur + 2] : 0x7FFFFFFF;
        } while (no0 == p + i + 1);     // skip empty dst runs (rare)
      }
    }
    p = pn; s2 = s2n;
  }
}

// ---------------- kernel 3: fused residual chain + final linear + skip ----
__global__ __launch_bounds__(512) void tail_kernel(
    const float* __restrict__ msged, const float* __restrict__ x, const float* __restrict__ u,
    const unsigned short* __restrict__ wfrag,
    const float* __restrict__ rb1, const float* __restrict__ rb2,
    const float* __restrict__ blast, float* __restrict__ out0, int N, int NRES){
  __shared__ __align__(16) unsigned short A_s[128*128];
  __shared__ __align__(16) unsigned short Bf[16384];
  const int t = threadIdx.x, wv = t >> 6, lane = t & 63;
  const int kg = lane >> 4, c = lane & 15;
  const int row0 = blockIdx.x * 128;

  float treg[8][4];
  #pragma unroll
  for (int ct = 0; ct < 8; ++ct)
    #pragma unroll
    for (int q = 0; q < 4; ++q){
      int gr = row0 + wv*16 + kg*4 + q;
      treg[ct][q] = (gr < N) ? msged[(size_t)gr*128 + ct*16 + c] : 0.f;
    }

  f32x4 acc[8];
  for (int l = 0; l < NRES; ++l){
    __syncthreads();                    // previous A_s/Bf readers done
    #pragma unroll
    for (int ct = 0; ct < 8; ++ct)
      #pragma unroll
      for (int q = 0; q < 4; ++q){
        int row = wv*16 + kg*4 + q, col = ct*16 + c;
        A_s[row*128 + (col ^ ((row & 7) << 3))] = f2bf_u(ssp_f(treg[ct][q]));
      }
    stage_bf512(Bf, wfrag + (size_t)(2 + 2*l)*16384, t);
    __syncthreads();
    mfma_gemm128s(A_s, Bf, wv*16, lane, acc);
    __syncthreads();                    // A_s/Bf reads done before overwrite
    #pragma unroll
    for (int ct = 0; ct < 8; ++ct){
      float bv = rb1[l*128 + ct*16 + c];
      #pragma unroll
      for (int q = 0; q < 4; ++q){
        int row = wv*16 + kg*4 + q, col = ct*16 + c;
        A_s[row*128 + (col ^ ((row & 7) << 3))] = f2bf_u(ssp_f(acc[ct][q] + bv));
      }
    }
    stage_bf512(Bf, wfrag + (size_t)(3 + 2*l)*16384, t);
    __syncthreads();
    mfma_gemm128s(A_s, Bf, wv*16, lane, acc);
    #pragma unroll
    for (int ct = 0; ct < 8; ++ct){
      float bv = rb2[l*128 + ct*16 + c];
      #pragma unroll
      for (int q = 0; q < 4; ++q) treg[ct][q] += acc[ct][q] + bv;
    }
  }
  __syncthreads();
  #pragma unroll
  for (int ct = 0; ct < 8; ++ct)
    #pragma unroll
    for (int q = 0; q < 4; ++q){
      int row = wv*16 + kg*4 + q, col = ct*16 + c;
      A_s[row*128 + (col ^ ((row & 7) << 3))] = f2bf_u(ssp_f(treg[ct][q]));
    }
  stage_bf512(Bf, wfrag + (size_t)(2 + 2*NRES)*16384, t);
  __syncthreads();
  mfma_gemm128s(A_s, Bf, wv*16, lane, acc);
  #pragma unroll
  for (int ct = 0; ct < 8; ++ct){
    int col = ct*16 + c;
    float bv = blast[col];
    float uv = u[col];
    #pragma unroll
    for (int q = 0; q < 4; ++q){
      int gr = row0 + wv*16 + kg*4 + q;
      if (gr < N){
        size_t idx = (size_t)gr*128 + col;
        out0[idx] = acc[ct][q] + bv + x[idx]*uv;
      }
    }
  }
}

extern "C" void kernel_launch(void* const* d_in, const int* in_sizes, int n_in,
                              void* d_out, int out_size, void* d_ws, size_t ws_size,
                              hipStream_t stream){
  const float* x     = (const float*)d_in[0];
  const void*  ei    = d_in[1];
  const float* ea    = (const float*)d_in[2];
  const float* Wsame = (const float*)d_in[3];
  const float* bsame = (const float*)d_in[4];
  const float* Wdiff = (const float*)d_in[5];
  const float* bdiff = (const float*)d_in[6];
  const float* WG    = (const float*)d_in[7];
  const float* rW1   = (const float*)d_in[8];
  const float* rb1   = (const float*)d_in[9];
  const float* rW2   = (const float*)d_in[10];
  const float* rb2   = (const float*)d_in[11];
  const float* Wlast = (const float*)d_in[12];
  const float* blast = (const float*)d_in[13];
  const float* u     = (const float*)d_in[14];

  const int N    = in_sizes[0] / 128;
  const int E    = in_sizes[1] / 2;
  int NRES = in_sizes[8] / (128*128);
  if (NRES > 6) NRES = 6;               // WPtrs capacity guard

  float* out0  = (float*)d_out;
  float* msged = (float*)d_out + (size_t)N * 128;   // second output, built in place

  auto align256 = [](size_t v){ return (v + 255) & ~(size_t)255; };
  const size_t o_h      = 256;
  const size_t o_count  = align256(o_h      + (size_t)N * 128 * 2);   // h is bf16
  const size_t o_off    = align256(o_count  + (size_t)N * 4);
  const size_t o_cur    = align256(o_off    + (size_t)(N + 1) * 4);
  const size_t o_se     = align256(o_cur    + (size_t)N * 4);
  const size_t o_bsum   = align256(o_se     + (size_t)E * 8);
  const size_t o_wfrag  = align256(o_bsum   + (size_t)4096 * 4);
  const size_t o_wgfrag = align256(o_wfrag  + (size_t)16 * 16384 * 2);

  int*   flag = (int*)d_ws;
  unsigned short* hbf = (unsigned short*)((char*)d_ws + o_h);
  int* count  = (int*)((char*)d_ws + o_count);
  int* offs   = (int*)((char*)d_ws + o_off);
  int* cur    = (int*)((char*)d_ws + o_cur);
  int2* se    = (int2*)((char*)d_ws + o_se);
  int* bsum   = (int*)((char*)d_ws + o_bsum);
  unsigned short* wfrag  = (unsigned short*)((char*)d_ws + o_wfrag);
  unsigned short* wgfrag = (unsigned short*)((char*)d_ws + o_wgfrag);
  (void)ws_size;

  const int nw = 3 + 2*NRES;            // same, diff, (W1,W2)*NRES, last
  WPtrs wp;
  wp.w[0] = Wsame;
  wp.w[1] = Wdiff;
  for (int l = 0; l < NRES; ++l){
    wp.w[2 + 2*l] = rW1 + (size_t)l*16384;
    wp.w[3 + 2*l] = rW2 + (size_t)l*16384;
  }
  wp.w[2 + 2*NRES] = Wlast;
  for (int i = nw; i < 16; ++i) wp.w[i] = Wlast;

  const int nb_node = (N + 127) / 128;
  const int nbk     = (N + 2047) / 2048;
  const int nb_edge = 2048;
  const int KW = nb_edge * 4 / 2;       // waves per feature-half

  setup_kernel<<<(N + 255) / 256, 256, 0, stream>>>((const unsigned*)ei, flag, count, N);
  prep_kernel<<<nw + 4, 256, 0, stream>>>(wp, nw, wfrag, WG, wgfrag);
  node_dual_kernel<<<nb_node, 512, 0, stream>>>(x, wfrag, bsame, bdiff, hbf, msged, N);

  hist_kernel<<<1024, 256, 0, stream>>>(ei, flag, count, E);
  scan1_kernel<<<nbk, 256, 0, stream>>>(count, bsum, N);
  scan2_kernel<<<1, 64, 0, stream>>>(bsum, offs, nbk, N);
  scan3_kernel<<<nbk, 256, 0, stream>>>(count, bsum, offs, cur, N);
  fill_kernel<<<1024, 256, 0, stream>>>(ei, flag, cur, se, E);

  edge_mfma_kernel<<<nb_edge, 256, 0, stream>>>(ea, wgfrag, hbf, se, offs, msged, N, E, KW);

  tail_kernel<<<nb_node, 512, 0, stream>>>(msged, x, u, wfrag, rb1, rb2, blast,
                                           out0, N, NRES);
}

// Round 9
// 367.413 us; speedup vs baseline: 1.0046x; 1.0046x over previous
//
#include <hip/hip_runtime.h>
#include <hip/hip_bf16.h>

#define LN2F 0.69314718055994530942f

typedef short bf16x8 __attribute__((ext_vector_type(8)));
typedef float f32x4  __attribute__((ext_vector_type(4)));

__device__ __forceinline__ float ssp_f(float t){
  // softplus(t) - ln2, numerically stable
  return fmaxf(t, 0.0f) + __logf(1.0f + __expf(-fabsf(t))) - LN2F;
}
__device__ __forceinline__ unsigned short f2bf_u(float f){
  __hip_bfloat16 b = __float2bfloat16(f);
  return *reinterpret_cast<unsigned short*>(&b);
}
__device__ __forceinline__ float bf2f(unsigned short u){
  __hip_bfloat16 b = *reinterpret_cast<__hip_bfloat16*>(&u);
  return __bfloat162float(b);
}

__device__ __forceinline__ int load_idx(const void* ei, int is32, size_t pos){
  return is32 ? ((const int*)ei)[pos] : (int)(((const long long*)ei)[pos]);
}

struct WPtrs { const float* w[16]; };

// ---------------- fused setup (zero count + idx-width detect) + weight prep -
// blocks [0,nzb): zero count (block 0 also detects int32 vs int64)
// blocks [nzb, nzb+nw): wfrag prep ; blocks [nzb+nw, nzb+nw+4): wgfrag prep
__global__ __launch_bounds__(256) void setup_prep_kernel(
    const unsigned* __restrict__ ei, int* __restrict__ flag,
    int* __restrict__ count, int N, int nzb,
    WPtrs p, int nw, unsigned short* __restrict__ wfrag,
    const float* __restrict__ WG, unsigned short* __restrict__ wgfrag){
  const int m = blockIdx.x;
  if (m < nzb){
    int i = m * 256 + threadIdx.x;
    if (i < N) count[i] = 0;
    if (m == 0){
      __shared__ int cnt;
      if (threadIdx.x == 0) cnt = 0;
      __syncthreads();
      int nz = 0;
      for (int k = threadIdx.x; k < 1024; k += 256)
        nz += (ei[2*k + 1] != 0u) ? 1 : 0;
      atomicAdd(&cnt, nz);
      __syncthreads();
      // int32 data: odd words are real indices (~all nonzero). int64: high words 0.
      if (threadIdx.x == 0) *flag = (cnt > 64) ? 1 : 0;
    }
  } else if (m < nzb + nw){
    const int w = m - nzb;
    const float* __restrict__ W = p.w[w];
    unsigned short* __restrict__ out = wfrag + (size_t)w * 16384;
    for (int q = threadIdx.x; q < 16384; q += 256){
      int i = q & 7, lane = (q >> 3) & 63, kt = (q >> 9) & 3, ct = q >> 11;
      int row = ct*16 + (lane & 15);
      int k   = kt*32 + (lane >> 4)*8 + i;
      out[q] = f2bf_u(W[row*128 + k]);
    }
  } else {
    const int b = m - nzb - nw;           // 0..3, each covers 2048 of 8192
    for (int qq = threadIdx.x; qq < 2048; qq += 256){
      int q = b*2048 + qq;
      int i = q & 7, lane = (q >> 3) & 63, kt = (q >> 9) & 1, nt = (q >> 10) & 3, half = q >> 12;
      int f = half*64 + nt*16 + (lane & 15);
      int k = kt*32 + (lane >> 4)*8 + i;
      wgfrag[q] = f2bf_u(WG[(size_t)f*64 + k]);
    }
  }
}

// ---------------- CSR build ------------------------------------------------
__global__ void hist_kernel(const void* __restrict__ ei, const int* __restrict__ flag,
                            int* __restrict__ count, int E){
  const int is32 = *flag;
  for (long long e = (long long)blockIdx.x * 256 + threadIdx.x; e < E;
       e += (long long)gridDim.x * 256){
    int d = load_idx(ei, is32, (size_t)((long long)E + e));
    atomicAdd(&count[d], 1);
  }
}

// three-pass scan: block sums -> serial scan of block sums -> local scan
__global__ __launch_bounds__(256) void scan1_kernel(const int* __restrict__ count,
                                                    int* __restrict__ bsum, int N){
  __shared__ int red[256];
  const int t = threadIdx.x;
  int i0 = blockIdx.x * 2048 + t * 8;
  int s = 0;
  #pragma unroll
  for (int r = 0; r < 8; ++r){ int i = i0 + r; s += (i < N) ? count[i] : 0; }
  red[t] = s;
  __syncthreads();
  for (int off = 128; off > 0; off >>= 1){
    if (t < off) red[t] += red[t + off];
    __syncthreads();
  }
  if (t == 0) bsum[blockIdx.x] = red[0];
}

__global__ void scan2_kernel(int* __restrict__ bsum, int* __restrict__ offs, int nb, int N){
  if (threadIdx.x == 0 && blockIdx.x == 0){
    int run = 0;
    for (int b = 0; b < nb; ++b){ int v = bsum[b]; bsum[b] = run; run += v; }
    offs[N] = run;
  }
}

__global__ __launch_bounds__(256) void scan3_kernel(const int* __restrict__ count,
                                                    const int* __restrict__ bsum,
                                                    int* __restrict__ offs,
                                                    int* __restrict__ cur, int N){
  __shared__ int red[256];
  const int t = threadIdx.x;
  int i0 = blockIdx.x * 2048 + t * 8;
  int v[8];
  int s = 0;
  #pragma unroll
  for (int r = 0; r < 8; ++r){ int i = i0 + r; v[r] = (i < N) ? count[i] : 0; s += v[r]; }
  red[t] = s;
  __syncthreads();
  #pragma unroll
  for (int off = 1; off < 256; off <<= 1){
    int tv = (t >= off) ? red[t - off] : 0;
    __syncthreads();
    red[t] += tv;
    __syncthreads();
  }
  int run = red[t] - s + bsum[blockIdx.x];
  #pragma unroll
  for (int r = 0; r < 8; ++r){
    int i = i0 + r;
    if (i < N){ offs[i] = run; cur[i] = run; }
    run += v[r];
  }
}

// se[slot] = (e, src), slots sorted by dst (CSR order)
__global__ void fill_kernel(const void* __restrict__ ei, const int* __restrict__ flag,
                            int* __restrict__ cur, int2* __restrict__ se, int E){
  const int is32 = *flag;
  for (long long e = (long long)blockIdx.x * 256 + threadIdx.x; e < E;
       e += (long long)gridDim.x * 256){
    int s = load_idx(ei, is32, (size_t)e);
    int d = load_idx(ei, is32, (size_t)((long long)E + e));
    int slot = atomicAdd(&cur[d], 1);
    se[slot] = make_int2((int)e, s);
  }
}

// ---------------- MFMA GEMM core: 128-row A tile (swizzled), K=128 --------
// A_s: bf16 [128][128], element (row,col) at row*128 + (col ^ ((row&7)<<3)).
// Bf: 16384 bf16 fragment-linear. acc[ct][q] = C[rbase+(lane>>4)*4+q][ct*16+(lane&15)]
__device__ __forceinline__ void mfma_gemm128s(const unsigned short* __restrict__ A_s,
                                              const unsigned short* __restrict__ Bf,
                                              int rbase, int lane, f32x4 acc[8]){
  #pragma unroll
  for (int ct = 0; ct < 8; ++ct) acc[ct] = (f32x4){0.f, 0.f, 0.f, 0.f};
  const int r  = rbase + (lane & 15);
  const int kg = lane >> 4;
  const int sw = (r & 7) << 3;
  #pragma unroll
  for (int kt = 0; kt < 4; ++kt){
    bf16x8 a = *(const bf16x8*)&A_s[r*128 + ((kt*32 + kg*8) ^ sw)];
    #pragma unroll
    for (int ct = 0; ct < 8; ++ct){
      bf16x8 b = *(const bf16x8*)&Bf[(size_t)((ct*4 + kt)*64 + lane)*8];
      acc[ct] = __builtin_amdgcn_mfma_f32_16x16x32_bf16(a, b, acc[ct], 0, 0, 0);
    }
  }
}

__device__ __forceinline__ void stage_bf512(unsigned short* __restrict__ Bf,
                                            const unsigned short* __restrict__ src, int t){
  #pragma unroll
  for (int it = 0; it < 4; ++it){
    int off = (it*512 + t) * 8;
    *(uint4*)&Bf[off] = *(const uint4*)&src[off];
  }
}

// ---------------- kernel 1: h = bf16(ssp(xa W_diff^T+b)), msged = ssp(xa W_same^T+b)
__global__ __launch_bounds__(512) void node_dual_kernel(
    const float* __restrict__ x, const unsigned short* __restrict__ wfrag,
    const float* __restrict__ bsame, const float* __restrict__ bdiff,
    unsigned short* __restrict__ hbf, float* __restrict__ msged, int N){
  __shared__ __align__(16) unsigned short A_s[128*128];
  __shared__ __align__(16) unsigned short Bf[16384];
  const int t = threadIdx.x, wv = t >> 6, lane = t & 63;
  const int kg = lane >> 4, c = lane & 15;
  const int row0 = blockIdx.x * 128;
  for (int q = t; q < 2048; q += 512){
    int row = q >> 4, c0 = (q & 15) * 8;
    float4 va = make_float4(0.f,0.f,0.f,0.f), vb = va;
    if (row0 + row < N){
      va = *(const float4*)&x[(size_t)(row0 + row)*128 + c0];
      vb = *(const float4*)&x[(size_t)(row0 + row)*128 + c0 + 4];
    }
    uint4 w;
    w.x = f2bf_u(ssp_f(va.x)) | ((unsigned)f2bf_u(ssp_f(va.y)) << 16);
    w.y = f2bf_u(ssp_f(va.z)) | ((unsigned)f2bf_u(ssp_f(va.w)) << 16);
    w.z = f2bf_u(ssp_f(vb.x)) | ((unsigned)f2bf_u(ssp_f(vb.y)) << 16);
    w.w = f2bf_u(ssp_f(vb.z)) | ((unsigned)f2bf_u(ssp_f(vb.w)) << 16);
    *(uint4*)&A_s[row*128 + (c0 ^ ((row & 7) << 3))] = w;
  }
  stage_bf512(Bf, wfrag, t);            // W_same
  __syncthreads();
  f32x4 acc[8];
  mfma_gemm128s(A_s, Bf, wv*16, lane, acc);
  #pragma unroll
  for (int ct = 0; ct < 8; ++ct){
    int col = ct*16 + c;
    float bv = bsame[col];
    #pragma unroll
    for (int q = 0; q < 4; ++q){
      int gr = row0 + wv*16 + kg*4 + q;
      if (gr < N) msged[(size_t)gr*128 + col] = ssp_f(acc[ct][q] + bv);
    }
  }
  __syncthreads();
  stage_bf512(Bf, wfrag + 16384, t);    // W_diff
  __syncthreads();
  mfma_gemm128s(A_s, Bf, wv*16, lane, acc);
  #pragma unroll
  for (int ct = 0; ct < 8; ++ct){
    int col = ct*16 + c;
    float bv = bdiff[col];
    #pragma unroll
    for (int q = 0; q < 4; ++q){
      int gr = row0 + wv*16 + kg*4 + q;
      if (gr < N) hbf[(size_t)gr*128 + col] = f2bf_u(ssp_f(acc[ct][q] + bv));
    }
  }
}

// ---------------- edge phase: swapped-operand MFMA gate + segmented reduce -
// acc = WG(A) x ea(B): lane holds (slot = lane&15, f = nt*16+kg*4+q).
// Reduce: batch-read P into registers (16 independent ds_reads, ONE wait),
// then fully-unrolled register reduce with wave-uniform boundary flushes.
__global__ __launch_bounds__(256) void edge_mfma_kernel(
    const float* __restrict__ ea, const unsigned short* __restrict__ wgfrag,
    const unsigned short* __restrict__ h, const int2* __restrict__ se,
    const int* __restrict__ offs, float* __restrict__ msged, int N, int E, int KW){
  __shared__ float P_s[4][16][67];
  const int t = threadIdx.x, wv = t >> 6, lane = t & 63;
  const int kg = lane >> 4, c = lane & 15;
  const int gw = blockIdx.x * 4 + wv;
  const int half = gw & 1;
  const int widx = gw >> 1;
  if (widx >= KW) return;
  long long tt0 = (long long)widx * E / KW;
  long long tt1 = (long long)(widx + 1) * E / KW;
  int lo = 0, hi = N;
  while (lo < hi){ int mid = (lo + hi) >> 1; if ((long long)offs[mid] < tt0) lo = mid + 1; else hi = mid; }
  const int d_lo = lo;
  hi = N;
  while (lo < hi){ int mid = (lo + hi) >> 1; if ((long long)offs[mid] < tt1) lo = mid + 1; else hi = mid; }
  const int d_hi = lo;
  if (d_lo >= d_hi) return;
  const int s_beg = offs[d_lo], s_end = offs[d_hi];
  if (s_beg >= s_end) return;

  // preload this half's WG fragments (A operand; reused for all batches)
  bf16x8 aw[4][2];
  #pragma unroll
  for (int nt = 0; nt < 4; ++nt)
    #pragma unroll
    for (int kt = 0; kt < 2; ++kt)
      aw[nt][kt] = *(const bf16x8*)&wgfrag[(size_t)((((half*4+nt)*2+kt)*64)+lane)*8];

  // boundary tracking with prefetched next-next offset
  int d_cur = d_lo;
  int no0 = offs[d_cur + 1];
  while (no0 == s_beg && d_cur + 1 < d_hi){ ++d_cur; no0 = offs[d_cur + 1]; }
  int no1 = (d_cur + 2 <= d_hi) ? offs[d_cur + 2] : 0x7FFFFFFF;

  float sum_v = 0.f;
  int p = s_beg;
  int nb = min(16, s_end - p);
  int2 s2 = se[p + min(c, nb - 1)];
  while (p < s_end){
    const int pn = p + 16;
    int2 s2n = s2;
    if (pn < s_end){
      int nbn = min(16, s_end - pn);
      s2n = se[pn + min(c, nbn - 1)];
    }
    // B fragments: this lane's slot-c ea row, k slice kg*8..kg*8+7 (+kt*32)
    const float* __restrict__ ra = &ea[(size_t)s2.x * 64 + kg*8];
    float4 e00 = *(const float4*)&ra[0];
    float4 e01 = *(const float4*)&ra[4];
    float4 e10 = *(const float4*)&ra[32];
    float4 e11 = *(const float4*)&ra[36];
    // h: lane-local src row, f = nt*16 + kg*4 + (0..3)
    const unsigned short* __restrict__ hr = &h[(size_t)s2.y*128 + half*64 + kg*4];
    ushort4 hu0 = *(const ushort4*)&hr[0];
    ushort4 hu1 = *(const ushort4*)&hr[16];
    ushort4 hu2 = *(const ushort4*)&hr[32];
    ushort4 hu3 = *(const ushort4*)&hr[48];

    bf16x8 be0, be1;
    unsigned short* b0p = (unsigned short*)&be0;
    unsigned short* b1p = (unsigned short*)&be1;
    b0p[0]=f2bf_u(e00.x); b0p[1]=f2bf_u(e00.y); b0p[2]=f2bf_u(e00.z); b0p[3]=f2bf_u(e00.w);
    b0p[4]=f2bf_u(e01.x); b0p[5]=f2bf_u(e01.y); b0p[6]=f2bf_u(e01.z); b0p[7]=f2bf_u(e01.w);
    b1p[0]=f2bf_u(e10.x); b1p[1]=f2bf_u(e10.y); b1p[2]=f2bf_u(e10.z); b1p[3]=f2bf_u(e10.w);
    b1p[4]=f2bf_u(e11.x); b1p[5]=f2bf_u(e11.y); b1p[6]=f2bf_u(e11.z); b1p[7]=f2bf_u(e11.w);

    f32x4 acc[4];
    #pragma unroll
    for (int nt = 0; nt < 4; ++nt){
      acc[nt] = (f32x4){0.f,0.f,0.f,0.f};
      acc[nt] = __builtin_amdgcn_mfma_f32_16x16x32_bf16(aw[nt][0], be0, acc[nt], 0, 0, 0);
      acc[nt] = __builtin_amdgcn_mfma_f32_16x16x32_bf16(aw[nt][1], be1, acc[nt], 0, 0, 0);
    }

    float hvv[4][4];
    hvv[0][0]=bf2f(hu0.x); hvv[0][1]=bf2f(hu0.y); hvv[0][2]=bf2f(hu0.z); hvv[0][3]=bf2f(hu0.w);
    hvv[1][0]=bf2f(hu1.x); hvv[1][1]=bf2f(hu1.y); hvv[1][2]=bf2f(hu1.z); hvv[1][3]=bf2f(hu1.w);
    hvv[2][0]=bf2f(hu2.x); hvv[2][1]=bf2f(hu2.y); hvv[2][2]=bf2f(hu2.z); hvv[2][3]=bf2f(hu2.w);
    hvv[3][0]=bf2f(hu3.x); hvv[3][1]=bf2f(hu3.y); hvv[3][2]=bf2f(hu3.z); hvv[3][3]=bf2f(hu3.w);

    // P[slot=c][f'] = gate * h   (2-way bank pattern on [16][67], free)
    #pragma unroll
    for (int nt = 0; nt < 4; ++nt)
      #pragma unroll
      for (int q = 0; q < 4; ++q)
        P_s[wv][c][nt*16 + kg*4 + q] = acc[nt][q] * hvv[nt][q];

    asm volatile("s_waitcnt lgkmcnt(0)" ::: "memory");  // P_s writes visible

    // batch-read P rows into registers: 16 independent conflict-free ds_reads
    float pv[16];
    #pragma unroll
    for (int i = 0; i < 16; ++i) pv[i] = P_s[wv][i][lane];

    // fully-unrolled register reduce; flushes are rare (avg ~1/batch)
    const int nbc = min(16, s_end - p);
    #pragma unroll
    for (int i = 0; i < 16; ++i){
      if (i < nbc){
        sum_v += pv[i];
        if (p + i + 1 == no0){
          msged[(size_t)d_cur*128 + half*64 + lane] += sum_v;   // owner-exclusive
          sum_v = 0.f;
          do {
            ++d_cur;
            no0 = no1;
            no1 = (d_cur + 2 <= d_hi) ? offs[d_cur + 2] : 0x7FFFFFFF;
          } while (no0 == p + i + 1);     // skip empty dst runs (rare)
        }
      }
    }
    p = pn; s2 = s2n;
  }
}

// ---------------- kernel 3: fused residual chain + final linear + skip ----
__global__ __launch_bounds__(512) void tail_kernel(
    const float* __restrict__ msged, const float* __restrict__ x, const float* __restrict__ u,
    const unsigned short* __restrict__ wfrag,
    const float* __restrict__ rb1, const float* __restrict__ rb2,
    const float* __restrict__ blast, float* __restrict__ out0, int N, int NRES){
  __shared__ __align__(16) unsigned short A_s[128*128];
  __shared__ __align__(16) unsigned short Bf[16384];
  const int t = threadIdx.x, wv = t >> 6, lane = t & 63;
  const int kg = lane >> 4, c = lane & 15;
  const int row0 = blockIdx.x * 128;

  float treg[8][4];
  #pragma unroll
  for (int ct = 0; ct < 8; ++ct)
    #pragma unroll
    for (int q = 0; q < 4; ++q){
      int gr = row0 + wv*16 + kg*4 + q;
      treg[ct][q] = (gr < N) ? msged[(size_t)gr*128 + ct*16 + c] : 0.f;
    }

  f32x4 acc[8];
  for (int l = 0; l < NRES; ++l){
    __syncthreads();                    // previous A_s/Bf readers done
    #pragma unroll
    for (int ct = 0; ct < 8; ++ct)
      #pragma unroll
      for (int q = 0; q < 4; ++q){
        int row = wv*16 + kg*4 + q, col = ct*16 + c;
        A_s[row*128 + (col ^ ((row & 7) << 3))] = f2bf_u(ssp_f(treg[ct][q]));
      }
    stage_bf512(Bf, wfrag + (size_t)(2 + 2*l)*16384, t);
    __syncthreads();
    mfma_gemm128s(A_s, Bf, wv*16, lane, acc);
    __syncthreads();                    // A_s/Bf reads done before overwrite
    #pragma unroll
    for (int ct = 0; ct < 8; ++ct){
      float bv = rb1[l*128 + ct*16 + c];
      #pragma unroll
      for (int q = 0; q < 4; ++q){
        int row = wv*16 + kg*4 + q, col = ct*16 + c;
        A_s[row*128 + (col ^ ((row & 7) << 3))] = f2bf_u(ssp_f(acc[ct][q] + bv));
      }
    }
    stage_bf512(Bf, wfrag + (size_t)(3 + 2*l)*16384, t);
    __syncthreads();
    mfma_gemm128s(A_s, Bf, wv*16, lane, acc);
    #pragma unroll
    for (int ct = 0; ct < 8; ++ct){
      float bv = rb2[l*128 + ct*16 + c];
      #pragma unroll
      for (int q = 0; q < 4; ++q) treg[ct][q] += acc[ct][q] + bv;
    }
  }
  __syncthreads();
  #pragma unroll
  for (int ct = 0; ct < 8; ++ct)
    #pragma unroll
    for (int q = 0; q < 4; ++q){
      int row = wv*16 + kg*4 + q, col = ct*16 + c;
      A_s[row*128 + (col ^ ((row & 7) << 3))] = f2bf_u(ssp_f(treg[ct][q]));
    }
  stage_bf512(Bf, wfrag + (size_t)(2 + 2*NRES)*16384, t);
  __syncthreads();
  mfma_gemm128s(A_s, Bf, wv*16, lane, acc);
  #pragma unroll
  for (int ct = 0; ct < 8; ++ct){
    int col = ct*16 + c;
    float bv = blast[col];
    float uv = u[col];
    #pragma unroll
    for (int q = 0; q < 4; ++q){
      int gr = row0 + wv*16 + kg*4 + q;
      if (gr < N){
        size_t idx = (size_t)gr*128 + col;
        out0[idx] = acc[ct][q] + bv + x[idx]*uv;
      }
    }
  }
}

extern "C" void kernel_launch(void* const* d_in, const int* in_sizes, int n_in,
                              void* d_out, int out_size, void* d_ws, size_t ws_size,
                              hipStream_t stream){
  const float* x     = (const float*)d_in[0];
  const void*  ei    = d_in[1];
  const float* ea    = (const float*)d_in[2];
  const float* Wsame = (const float*)d_in[3];
  const float* bsame = (const float*)d_in[4];
  const float* Wdiff = (const float*)d_in[5];
  const float* bdiff = (const float*)d_in[6];
  const float* WG    = (const float*)d_in[7];
  const float* rW1   = (const float*)d_in[8];
  const float* rb1   = (const float*)d_in[9];
  const float* rW2   = (const float*)d_in[10];
  const float* rb2   = (const float*)d_in[11];
  const float* Wlast = (const float*)d_in[12];
  const float* blast = (const float*)d_in[13];
  const float* u     = (const float*)d_in[14];

  const int N    = in_sizes[0] / 128;
  const int E    = in_sizes[1] / 2;
  int NRES = in_sizes[8] / (128*128);
  if (NRES > 6) NRES = 6;               // WPtrs capacity guard

  float* out0  = (float*)d_out;
  float* msged = (float*)d_out + (size_t)N * 128;   // second output, built in place

  auto align256 = [](size_t v){ return (v + 255) & ~(size_t)255; };
  const size_t o_h      = 256;
  const size_t o_count  = align256(o_h      + (size_t)N * 128 * 2);   // h is bf16
  const size_t o_off    = align256(o_count  + (size_t)N * 4);
  const size_t o_cur    = align256(o_off    + (size_t)(N + 1) * 4);
  const size_t o_se     = align256(o_cur    + (size_t)N * 4);
  const size_t o_bsum   = align256(o_se     + (size_t)E * 8);
  const size_t o_wfrag  = align256(o_bsum   + (size_t)4096 * 4);
  const size_t o_wgfrag = align256(o_wfrag  + (size_t)16 * 16384 * 2);

  int*   flag = (int*)d_ws;
  unsigned short* hbf = (unsigned short*)((char*)d_ws + o_h);
  int* count  = (int*)((char*)d_ws + o_count);
  int* offs   = (int*)((char*)d_ws + o_off);
  int* cur    = (int*)((char*)d_ws + o_cur);
  int2* se    = (int2*)((char*)d_ws + o_se);
  int* bsum   = (int*)((char*)d_ws + o_bsum);
  unsigned short* wfrag  = (unsigned short*)((char*)d_ws + o_wfrag);
  unsigned short* wgfrag = (unsigned short*)((char*)d_ws + o_wgfrag);
  (void)ws_size;

  const int nw = 3 + 2*NRES;            // same, diff, (W1,W2)*NRES, last
  WPtrs wp;
  wp.w[0] = Wsame;
  wp.w[1] = Wdiff;
  for (int l = 0; l < NRES; ++l){
    wp.w[2 + 2*l] = rW1 + (size_t)l*16384;
    wp.w[3 + 2*l] = rW2 + (size_t)l*16384;
  }
  wp.w[2 + 2*NRES] = Wlast;
  for (int i = nw; i < 16; ++i) wp.w[i] = Wlast;

  const int nb_node = (N + 127) / 128;
  const int nzb     = (N + 255) / 256;
  const int nbk     = (N + 2047) / 2048;
  const int nb_edge = 2048;
  const int KW = nb_edge * 4 / 2;       // waves per feature-half

  setup_prep_kernel<<<nzb + nw + 4, 256, 0, stream>>>((const unsigned*)ei, flag, count, N,
                                                      nzb, wp, nw, wfrag, WG, wgfrag);
  node_dual_kernel<<<nb_node, 512, 0, stream>>>(x, wfrag, bsame, bdiff, hbf, msged, N);

  hist_kernel<<<1024, 256, 0, stream>>>(ei, flag, count, E);
  scan1_kernel<<<nbk, 256, 0, stream>>>(count, bsum, N);
  scan2_kernel<<<1, 64, 0, stream>>>(bsum, offs, nbk, N);
  scan3_kernel<<<nbk, 256, 0, stream>>>(count, bsum, offs, cur, N);
  fill_kernel<<<1024, 256, 0, stream>>>(ei, flag, cur, se, E);

  edge_mfma_kernel<<<nb_edge, 256, 0, stream>>>(ea, wgfrag, hbf, se, offs, msged, N, E, KW);

  tail_kernel<<<nb_node, 512, 0, stream>>>(msged, x, u, wfrag, rb1, rb2, blast,
                                           out0, N, NRES);
}

// Round 10
// 360.695 us; speedup vs baseline: 1.0233x; 1.0186x over previous
//
#include <hip/hip_runtime.h>
#include <hip/hip_bf16.h>

#define LN2F 0.69314718055994530942f

typedef short bf16x8 __attribute__((ext_vector_type(8)));
typedef float f32x4  __attribute__((ext_vector_type(4)));

__device__ __forceinline__ float ssp_f(float t){
  // softplus(t) - ln2, numerically stable
  return fmaxf(t, 0.0f) + __logf(1.0f + __expf(-fabsf(t))) - LN2F;
}
__device__ __forceinline__ unsigned short f2bf_u(float f){
  __hip_bfloat16 b = __float2bfloat16(f);
  return *reinterpret_cast<unsigned short*>(&b);
}
__device__ __forceinline__ float bf2f(unsigned short u){
  __hip_bfloat16 b = *reinterpret_cast<__hip_bfloat16*>(&u);
  return __bfloat162float(b);
}

__device__ __forceinline__ int load_idx(const void* ei, int is32, size_t pos){
  return is32 ? ((const int*)ei)[pos] : (int)(((const long long*)ei)[pos]);
}

struct WPtrs { const float* w[16]; };

// ---------------- fused setup (zero count + idx-width detect) + weight prep -
__global__ __launch_bounds__(256) void setup_prep_kernel(
    const unsigned* __restrict__ ei, int* __restrict__ flag,
    int* __restrict__ count, int N, int nzb,
    WPtrs p, int nw, unsigned short* __restrict__ wfrag,
    const float* __restrict__ WG, unsigned short* __restrict__ wgfrag){
  const int m = blockIdx.x;
  if (m < nzb){
    int i = m * 256 + threadIdx.x;
    if (i < N) count[i] = 0;
    if (m == 0){
      __shared__ int cnt;
      if (threadIdx.x == 0) cnt = 0;
      __syncthreads();
      int nz = 0;
      for (int k = threadIdx.x; k < 1024; k += 256)
        nz += (ei[2*k + 1] != 0u) ? 1 : 0;
      atomicAdd(&cnt, nz);
      __syncthreads();
      // int32 data: odd words are real indices (~all nonzero). int64: high words 0.
      if (threadIdx.x == 0) *flag = (cnt > 64) ? 1 : 0;
    }
  } else if (m < nzb + nw){
    const int w = m - nzb;
    const float* __restrict__ W = p.w[w];
    unsigned short* __restrict__ out = wfrag + (size_t)w * 16384;
    for (int q = threadIdx.x; q < 16384; q += 256){
      int i = q & 7, lane = (q >> 3) & 63, kt = (q >> 9) & 3, ct = q >> 11;
      int row = ct*16 + (lane & 15);
      int k   = kt*32 + (lane >> 4)*8 + i;
      out[q] = f2bf_u(W[row*128 + k]);
    }
  } else {
    const int b = m - nzb - nw;           // 0..3, each covers 2048 of 8192
    for (int qq = threadIdx.x; qq < 2048; qq += 256){
      int q = b*2048 + qq;
      int i = q & 7, lane = (q >> 3) & 63, kt = (q >> 9) & 1, nt = q >> 10; // nt 0..7
      int f = nt*16 + (lane & 15);
      int k = kt*32 + (lane >> 4)*8 + i;
      wgfrag[q] = f2bf_u(WG[(size_t)f*64 + k]);
    }
  }
}

// ---------------- CSR build ------------------------------------------------
__global__ void hist_kernel(const void* __restrict__ ei, const int* __restrict__ flag,
                            int* __restrict__ count, int E){
  const int is32 = *flag;
  for (long long e = (long long)blockIdx.x * 256 + threadIdx.x; e < E;
       e += (long long)gridDim.x * 256){
    int d = load_idx(ei, is32, (size_t)((long long)E + e));
    atomicAdd(&count[d], 1);
  }
}

__global__ __launch_bounds__(256) void scan1_kernel(const int* __restrict__ count,
                                                    int* __restrict__ bsum, int N){
  __shared__ int red[256];
  const int t = threadIdx.x;
  int i0 = blockIdx.x * 2048 + t * 8;
  int s = 0;
  #pragma unroll
  for (int r = 0; r < 8; ++r){ int i = i0 + r; s += (i < N) ? count[i] : 0; }
  red[t] = s;
  __syncthreads();
  for (int off = 128; off > 0; off >>= 1){
    if (t < off) red[t] += red[t + off];
    __syncthreads();
  }
  if (t == 0) bsum[blockIdx.x] = red[0];
}

__global__ void scan2_kernel(int* __restrict__ bsum, int* __restrict__ offs, int nb, int N){
  if (threadIdx.x == 0 && blockIdx.x == 0){
    int run = 0;
    for (int b = 0; b < nb; ++b){ int v = bsum[b]; bsum[b] = run; run += v; }
    offs[N] = run;
  }
}

__global__ __launch_bounds__(256) void scan3_kernel(const int* __restrict__ count,
                                                    const int* __restrict__ bsum,
                                                    int* __restrict__ offs,
                                                    int* __restrict__ cur, int N){
  __shared__ int red[256];
  const int t = threadIdx.x;
  int i0 = blockIdx.x * 2048 + t * 8;
  int v[8];
  int s = 0;
  #pragma unroll
  for (int r = 0; r < 8; ++r){ int i = i0 + r; v[r] = (i < N) ? count[i] : 0; s += v[r]; }
  red[t] = s;
  __syncthreads();
  #pragma unroll
  for (int off = 1; off < 256; off <<= 1){
    int tv = (t >= off) ? red[t - off] : 0;
    __syncthreads();
    red[t] += tv;
    __syncthreads();
  }
  int run = red[t] - s + bsum[blockIdx.x];
  #pragma unroll
  for (int r = 0; r < 8; ++r){
    int i = i0 + r;
    if (i < N){ offs[i] = run; cur[i] = run; }
    run += v[r];
  }
}

// se[slot] = (e, src), slots sorted by dst (CSR order)
__global__ void fill_kernel(const void* __restrict__ ei, const int* __restrict__ flag,
                            int* __restrict__ cur, int2* __restrict__ se, int E){
  const int is32 = *flag;
  for (long long e = (long long)blockIdx.x * 256 + threadIdx.x; e < E;
       e += (long long)gridDim.x * 256){
    int s = load_idx(ei, is32, (size_t)e);
    int d = load_idx(ei, is32, (size_t)((long long)E + e));
    int slot = atomicAdd(&cur[d], 1);
    se[slot] = make_int2((int)e, s);
  }
}

// ---------------- MFMA GEMM core: 128-row A tile (swizzled), K=128 --------
__device__ __forceinline__ void mfma_gemm128s(const unsigned short* __restrict__ A_s,
                                              const unsigned short* __restrict__ Bf,
                                              int rbase, int lane, f32x4 acc[8]){
  #pragma unroll
  for (int ct = 0; ct < 8; ++ct) acc[ct] = (f32x4){0.f, 0.f, 0.f, 0.f};
  const int r  = rbase + (lane & 15);
  const int kg = lane >> 4;
  const int sw = (r & 7) << 3;
  #pragma unroll
  for (int kt = 0; kt < 4; ++kt){
    bf16x8 a = *(const bf16x8*)&A_s[r*128 + ((kt*32 + kg*8) ^ sw)];
    #pragma unroll
    for (int ct = 0; ct < 8; ++ct){
      bf16x8 b = *(const bf16x8*)&Bf[(size_t)((ct*4 + kt)*64 + lane)*8];
      acc[ct] = __builtin_amdgcn_mfma_f32_16x16x32_bf16(a, b, acc[ct], 0, 0, 0);
    }
  }
}

__device__ __forceinline__ void stage_bf512(unsigned short* __restrict__ Bf,
                                            const unsigned short* __restrict__ src, int t){
  #pragma unroll
  for (int it = 0; it < 4; ++it){
    int off = (it*512 + t) * 8;
    *(uint4*)&Bf[off] = *(const uint4*)&src[off];
  }
}

// ---------------- kernel 1: h = bf16(ssp(xa W_diff^T+b)), msged = ssp(xa W_same^T+b)
__global__ __launch_bounds__(512) void node_dual_kernel(
    const float* __restrict__ x, const unsigned short* __restrict__ wfrag,
    const float* __restrict__ bsame, const float* __restrict__ bdiff,
    unsigned short* __restrict__ hbf, float* __restrict__ msged, int N){
  __shared__ __align__(16) unsigned short A_s[128*128];
  __shared__ __align__(16) unsigned short Bf[16384];
  const int t = threadIdx.x, wv = t >> 6, lane = t & 63;
  const int kg = lane >> 4, c = lane & 15;
  const int row0 = blockIdx.x * 128;
  for (int q = t; q < 2048; q += 512){
    int row = q >> 4, c0 = (q & 15) * 8;
    float4 va = make_float4(0.f,0.f,0.f,0.f), vb = va;
    if (row0 + row < N){
      va = *(const float4*)&x[(size_t)(row0 + row)*128 + c0];
      vb = *(const float4*)&x[(size_t)(row0 + row)*128 + c0 + 4];
    }
    uint4 w;
    w.x = f2bf_u(ssp_f(va.x)) | ((unsigned)f2bf_u(ssp_f(va.y)) << 16);
    w.y = f2bf_u(ssp_f(va.z)) | ((unsigned)f2bf_u(ssp_f(va.w)) << 16);
    w.z = f2bf_u(ssp_f(vb.x)) | ((unsigned)f2bf_u(ssp_f(vb.y)) << 16);
    w.w = f2bf_u(ssp_f(vb.z)) | ((unsigned)f2bf_u(ssp_f(vb.w)) << 16);
    *(uint4*)&A_s[row*128 + (c0 ^ ((row & 7) << 3))] = w;
  }
  stage_bf512(Bf, wfrag, t);            // W_same
  __syncthreads();
  f32x4 acc[8];
  mfma_gemm128s(A_s, Bf, wv*16, lane, acc);
  #pragma unroll
  for (int ct = 0; ct < 8; ++ct){
    int col = ct*16 + c;
    float bv = bsame[col];
    #pragma unroll
    for (int q = 0; q < 4; ++q){
      int gr = row0 + wv*16 + kg*4 + q;
      if (gr < N) msged[(size_t)gr*128 + col] = ssp_f(acc[ct][q] + bv);
    }
  }
  __syncthreads();
  stage_bf512(Bf, wfrag + 16384, t);    // W_diff
  __syncthreads();
  mfma_gemm128s(A_s, Bf, wv*16, lane, acc);
  #pragma unroll
  for (int ct = 0; ct < 8; ++ct){
    int col = ct*16 + c;
    float bv = bdiff[col];
    #pragma unroll
    for (int q = 0; q < 4; ++q){
      int gr = row0 + wv*16 + kg*4 + q;
      if (gr < N) hbf[(size_t)gr*128 + col] = f2bf_u(ssp_f(acc[ct][q] + bv));
    }
  }
}

// ---------------- edge phase: merged-halves MFMA gate + segmented reduce --
// One wave owns a dst-aligned slot range and ALL 128 features. Per 16-slot
// batch: ea rows read ONCE (B operand), h rows staged to LDS once (16B/lane),
// gate for f=0..127 via 16 MFMAs (WG fragments in 64 VGPRs), then a reduce
// that multiplies gate*h from LDS and flushes full 512B msged rows per dst.
__global__ __launch_bounds__(256) void edge_mfma_kernel(
    const float* __restrict__ ea, const unsigned short* __restrict__ wgfrag,
    const unsigned short* __restrict__ h, const int2* __restrict__ se,
    const int* __restrict__ offs, float* __restrict__ msged, int N, int E, int KW){
  __shared__ float gate_s[4][16][132];
  __shared__ unsigned short h_s[4][16][136];
  const int t = threadIdx.x, wv = t >> 6, lane = t & 63;
  const int kg = lane >> 4, c = lane & 15;
  const int widx = blockIdx.x * 4 + wv;
  if (widx >= KW) return;
  long long tt0 = (long long)widx * E / KW;
  long long tt1 = (long long)(widx + 1) * E / KW;
  int lo = 0, hi = N;
  while (lo < hi){ int mid = (lo + hi) >> 1; if ((long long)offs[mid] < tt0) lo = mid + 1; else hi = mid; }
  const int d_lo = lo;
  hi = N;
  while (lo < hi){ int mid = (lo + hi) >> 1; if ((long long)offs[mid] < tt1) lo = mid + 1; else hi = mid; }
  const int d_hi = lo;
  if (d_lo >= d_hi) return;
  const int s_beg = offs[d_lo], s_end = offs[d_hi];
  if (s_beg >= s_end) return;

  // WG fragments for all 8 column-tiles (A operand), 64 VGPRs, loaded once
  bf16x8 aw[8][2];
  #pragma unroll
  for (int nt = 0; nt < 8; ++nt)
    #pragma unroll
    for (int kt = 0; kt < 2; ++kt)
      aw[nt][kt] = *(const bf16x8*)&wgfrag[(size_t)(((nt*2+kt)*64)+lane)*8];

  // boundary tracking with prefetched next-next offset
  int d_cur = d_lo;
  int no0 = offs[d_cur + 1];
  while (no0 == s_beg && d_cur + 1 < d_hi){ ++d_cur; no0 = offs[d_cur + 1]; }
  int no1 = (d_cur + 2 <= d_hi) ? offs[d_cur + 2] : 0x7FFFFFFF;

  float sum0 = 0.f, sum1 = 0.f;
  int p = s_beg;
  int nb = min(16, s_end - p);
  int2 s2 = se[p + min(c, nb - 1)];
  while (p < s_end){
    const int pn = p + 16;
    int2 s2n = s2;
    if (pn < s_end){
      int nbn = min(16, s_end - pn);
      s2n = se[pn + min(c, nbn - 1)];
    }
    // B fragments: lane's slot-c ea row, k slice kg*8..kg*8+7 (+kt*32) — read ONCE
    const float* __restrict__ ra = &ea[(size_t)s2.x * 64 + kg*8];
    float4 e00 = *(const float4*)&ra[0];
    float4 e01 = *(const float4*)&ra[4];
    float4 e10 = *(const float4*)&ra[32];
    float4 e11 = *(const float4*)&ra[36];

    // h staging: 16 rows x 256B -> LDS, 16B per lane per instr (4 instr)
    uint4 hreg[4];
    #pragma unroll
    for (int it = 0; it < 4; ++it){
      int j = it*64 + lane;
      int row = j >> 4, seg = j & 15;
      int sr = __shfl(s2.y, row, 16);
      hreg[it] = *(const uint4*)&h[(size_t)sr*128 + seg*8];
    }
    #pragma unroll
    for (int it = 0; it < 4; ++it){
      int j = it*64 + lane;
      int row = j >> 4, seg = j & 15;
      *(uint4*)&h_s[wv][row][seg*8] = hreg[it];
    }

    bf16x8 be0, be1;
    unsigned short* b0p = (unsigned short*)&be0;
    unsigned short* b1p = (unsigned short*)&be1;
    b0p[0]=f2bf_u(e00.x); b0p[1]=f2bf_u(e00.y); b0p[2]=f2bf_u(e00.z); b0p[3]=f2bf_u(e00.w);
    b0p[4]=f2bf_u(e01.x); b0p[5]=f2bf_u(e01.y); b0p[6]=f2bf_u(e01.z); b0p[7]=f2bf_u(e01.w);
    b1p[0]=f2bf_u(e10.x); b1p[1]=f2bf_u(e10.y); b1p[2]=f2bf_u(e10.z); b1p[3]=f2bf_u(e10.w);
    b1p[4]=f2bf_u(e11.x); b1p[5]=f2bf_u(e11.y); b1p[6]=f2bf_u(e11.z); b1p[7]=f2bf_u(e11.w);

    // gate for all 128 f: 16 MFMAs; write each f32x4 straight to LDS
    #pragma unroll
    for (int nt = 0; nt < 8; ++nt){
      f32x4 acc = (f32x4){0.f,0.f,0.f,0.f};
      acc = __builtin_amdgcn_mfma_f32_16x16x32_bf16(aw[nt][0], be0, acc, 0, 0, 0);
      acc = __builtin_amdgcn_mfma_f32_16x16x32_bf16(aw[nt][1], be1, acc, 0, 0, 0);
      *(f32x4*)&gate_s[wv][c][nt*16 + kg*4] = acc;
    }

    asm volatile("s_waitcnt lgkmcnt(0)" ::: "memory");  // h_s + gate_s visible

    const int nbc = min(16, s_end - p);
    #pragma unroll
    for (int i = 0; i < 16; ++i){
      if (i < nbc){
        float g0 = gate_s[wv][i][lane];
        float g1 = gate_s[wv][i][lane + 64];
        float h0 = bf2f(h_s[wv][i][lane]);
        float h1 = bf2f(h_s[wv][i][lane + 64]);
        sum0 = __builtin_fmaf(g0, h0, sum0);
        sum1 = __builtin_fmaf(g1, h1, sum1);
        if (p + i + 1 == no0){
          float* mp = &msged[(size_t)d_cur*128 + lane];
          mp[0]  += sum0;                 // owner-exclusive, full 512B row
          mp[64] += sum1;
          sum0 = 0.f; sum1 = 0.f;
          do {
            ++d_cur;
            no0 = no1;
            no1 = (d_cur + 2 <= d_hi) ? offs[d_cur + 2] : 0x7FFFFFFF;
          } while (no0 == p + i + 1);     // skip empty dst runs (rare)
        }
      }
    }
    p = pn; s2 = s2n;
  }
}

// ---------------- kernel 3: fused residual chain + final linear + skip ----
__global__ __launch_bounds__(512) void tail_kernel(
    const float* __restrict__ msged, const float* __restrict__ x, const float* __restrict__ u,
    const unsigned short* __restrict__ wfrag,
    const float* __restrict__ rb1, const float* __restrict__ rb2,
    const float* __restrict__ blast, float* __restrict__ out0, int N, int NRES){
  __shared__ __align__(16) unsigned short A_s[128*128];
  __shared__ __align__(16) unsigned short Bf[16384];
  const int t = threadIdx.x, wv = t >> 6, lane = t & 63;
  const int kg = lane >> 4, c = lane & 15;
  const int row0 = blockIdx.x * 128;

  float treg[8][4];
  #pragma unroll
  for (int ct = 0; ct < 8; ++ct)
    #pragma unroll
    for (int q = 0; q < 4; ++q){
      int gr = row0 + wv*16 + kg*4 + q;
      treg[ct][q] = (gr < N) ? msged[(size_t)gr*128 + ct*16 + c] : 0.f;
    }

  f32x4 acc[8];
  for (int l = 0; l < NRES; ++l){
    __syncthreads();                    // previous A_s/Bf readers done
    #pragma unroll
    for (int ct = 0; ct < 8; ++ct)
      #pragma unroll
      for (int q = 0; q < 4; ++q){
        int row = wv*16 + kg*4 + q, col = ct*16 + c;
        A_s[row*128 + (col ^ ((row & 7) << 3))] = f2bf_u(ssp_f(treg[ct][q]));
      }
    stage_bf512(Bf, wfrag + (size_t)(2 + 2*l)*16384, t);
    __syncthreads();
    mfma_gemm128s(A_s, Bf, wv*16, lane, acc);
    __syncthreads();                    // A_s/Bf reads done before overwrite
    #pragma unroll
    for (int ct = 0; ct < 8; ++ct){
      float bv = rb1[l*128 + ct*16 + c];
      #pragma unroll
      for (int q = 0; q < 4; ++q){
        int row = wv*16 + kg*4 + q, col = ct*16 + c;
        A_s[row*128 + (col ^ ((row & 7) << 3))] = f2bf_u(ssp_f(acc[ct][q] + bv));
      }
    }
    stage_bf512(Bf, wfrag + (size_t)(3 + 2*l)*16384, t);
    __syncthreads();
    mfma_gemm128s(A_s, Bf, wv*16, lane, acc);
    #pragma unroll
    for (int ct = 0; ct < 8; ++ct){
      float bv = rb2[l*128 + ct*16 + c];
      #pragma unroll
      for (int q = 0; q < 4; ++q) treg[ct][q] += acc[ct][q] + bv;
    }
  }
  __syncthreads();
  #pragma unroll
  for (int ct = 0; ct < 8; ++ct)
    #pragma unroll
    for (int q = 0; q < 4; ++q){
      int row = wv*16 + kg*4 + q, col = ct*16 + c;
      A_s[row*128 + (col ^ ((row & 7) << 3))] = f2bf_u(ssp_f(treg[ct][q]));
    }
  stage_bf512(Bf, wfrag + (size_t)(2 + 2*NRES)*16384, t);
  __syncthreads();
  mfma_gemm128s(A_s, Bf, wv*16, lane, acc);
  #pragma unroll
  for (int ct = 0; ct < 8; ++ct){
    int col = ct*16 + c;
    float bv = blast[col];
    float uv = u[col];
    #pragma unroll
    for (int q = 0; q < 4; ++q){
      int gr = row0 + wv*16 + kg*4 + q;
      if (gr < N){
        size_t idx = (size_t)gr*128 + col;
        out0[idx] = acc[ct][q] + bv + x[idx]*uv;
      }
    }
  }
}

extern "C" void kernel_launch(void* const* d_in, const int* in_sizes, int n_in,
                              void* d_out, int out_size, void* d_ws, size_t ws_size,
                              hipStream_t stream){
  const float* x     = (const float*)d_in[0];
  const void*  ei    = d_in[1];
  const float* ea    = (const float*)d_in[2];
  const float* Wsame = (const float*)d_in[3];
  const float* bsame = (const float*)d_in[4];
  const float* Wdiff = (const float*)d_in[5];
  const float* bdiff = (const float*)d_in[6];
  const float* WG    = (const float*)d_in[7];
  const float* rW1   = (const float*)d_in[8];
  const float* rb1   = (const float*)d_in[9];
  const float* rW2   = (const float*)d_in[10];
  const float* rb2   = (const float*)d_in[11];
  const float* Wlast = (const float*)d_in[12];
  const float* blast = (const float*)d_in[13];
  const float* u     = (const float*)d_in[14];

  const int N    = in_sizes[0] / 128;
  const int E    = in_sizes[1] / 2;
  int NRES = in_sizes[8] / (128*128);
  if (NRES > 6) NRES = 6;               // WPtrs capacity guard

  float* out0  = (float*)d_out;
  float* msged = (float*)d_out + (size_t)N * 128;   // second output, built in place

  auto align256 = [](size_t v){ return (v + 255) & ~(size_t)255; };
  const size_t o_h      = 256;
  const size_t o_count  = align256(o_h      + (size_t)N * 128 * 2);   // h is bf16
  const size_t o_off    = align256(o_count  + (size_t)N * 4);
  const size_t o_cur    = align256(o_off    + (size_t)(N + 1) * 4);
  const size_t o_se     = align256(o_cur    + (size_t)N * 4);
  const size_t o_bsum   = align256(o_se     + (size_t)E * 8);
  const size_t o_wfrag  = align256(o_bsum   + (size_t)4096 * 4);
  const size_t o_wgfrag = align256(o_wfrag  + (size_t)16 * 16384 * 2);

  int*   flag = (int*)d_ws;
  unsigned short* hbf = (unsigned short*)((char*)d_ws + o_h);
  int* count  = (int*)((char*)d_ws + o_count);
  int* offs   = (int*)((char*)d_ws + o_off);
  int* cur    = (int*)((char*)d_ws + o_cur);
  int2* se    = (int2*)((char*)d_ws + o_se);
  int* bsum   = (int*)((char*)d_ws + o_bsum);
  unsigned short* wfrag  = (unsigned short*)((char*)d_ws + o_wfrag);
  unsigned short* wgfrag = (unsigned short*)((char*)d_ws + o_wgfrag);
  (void)ws_size;

  const int nw = 3 + 2*NRES;            // same, diff, (W1,W2)*NRES, last
  WPtrs wp;
  wp.w[0] = Wsame;
  wp.w[1] = Wdiff;
  for (int l = 0; l < NRES; ++l){
    wp.w[2 + 2*l] = rW1 + (size_t)l*16384;
    wp.w[3 + 2*l] = rW2 + (size_t)l*16384;
  }
  wp.w[2 + 2*NRES] = Wlast;
  for (int i = nw; i < 16; ++i) wp.w[i] = Wlast;

  const int nb_node = (N + 127) / 128;
  const int nzb     = (N + 255) / 256;
  const int nbk     = (N + 2047) / 2048;
  const int nb_edge = 2048;
  const int KW = nb_edge * 4;           // one wave covers all 128 features

  setup_prep_kernel<<<nzb + nw + 4, 256, 0, stream>>>((const unsigned*)ei, flag, count, N,
                                                      nzb, wp, nw, wfrag, WG, wgfrag);
  node_dual_kernel<<<nb_node, 512, 0, stream>>>(x, wfrag, bsame, bdiff, hbf, msged, N);

  hist_kernel<<<1024, 256, 0, stream>>>(ei, flag, count, E);
  scan1_kernel<<<nbk, 256, 0, stream>>>(count, bsum, N);
  scan2_kernel<<<1, 64, 0, stream>>>(bsum, offs, nbk, N);
  scan3_kernel<<<nbk, 256, 0, stream>>>(count, bsum, offs, cur, N);
  fill_kernel<<<1024, 256, 0, stream>>>(ei, flag, cur, se, E);

  edge_mfma_kernel<<<nb_edge, 256, 0, stream>>>(ea, wgfrag, hbf, se, offs, msged, N, E, KW);

  tail_kernel<<<nb_node, 512, 0, stream>>>(msged, x, u, wfrag, rb1, rb2, blast,
                                           out0, N, NRES);
}